// Round 5
// baseline (215.904 us; speedup 1.0000x reference)
//
#include <hip/hip_runtime.h>
#include <hip/hip_bf16.h>
#include <math.h>

#define BDIM 8192
#define DDIM 2048
#define CDIM 1000
#define NPAD 1024
#define BK   64

// ws layout (bytes): xb bf16 [8192*2048] = 33554432 ; Bt bf16 [1024*2048] = 4194304 ;
// C1 fp32 partial [8192*1000] = 32768000 @ offset 37748736 ; total 70516736
#define WS_C1_OFFSET  37748736ULL
#define WS_NEED       70516736ULL

typedef __attribute__((ext_vector_type(8))) short short8;
typedef __attribute__((ext_vector_type(4))) float floatx4;

__device__ __forceinline__ unsigned short f2bf(float f) {
    union { float f; unsigned u; } a; a.f = f;
    unsigned u = a.u;
    u = (u + 0x7fff + ((u >> 16) & 1)) >> 16;   // RNE, finite inputs
    return (unsigned short)u;
}

__device__ __forceinline__ void async_copy16(const void* gp, void* lp) {
    __builtin_amdgcn_global_load_lds(
        (const __attribute__((address_space(1))) void*)gp,
        (__attribute__((address_space(3))) void*)lp,
        16, 0, 0);
}

// ---- kernel 1: fused x->bf16 (blocks 0..16383) and W->Bt transpose (blocks 16384..18431) ----
__global__ __launch_bounds__(256) void cvt_kernel(
    const float* __restrict__ x, unsigned short* __restrict__ xb,
    const float* __restrict__ W, unsigned short* __restrict__ Bt)
{
    const int blk = blockIdx.x;
    const int t   = threadIdx.x;
    if (blk < 16384) {
        int i = blk * 256 + t;
        float4 v = ((const float4*)x)[i];
        ushort4 o;
        o.x = f2bf(v.x); o.y = f2bf(v.y); o.z = f2bf(v.z); o.w = f2bf(v.w);
        ((ushort4*)xb)[i] = o;
    } else {
        __shared__ float tile[32][33];
        const int b2 = blk - 16384;          // 64 k-tiles x 32 n-tiles
        const int k0 = (b2 & 63) * 32;
        const int n0 = (b2 >> 6) * 32;
        const int tx = t & 31, ty = t >> 5;  // 32 x 8
        #pragma unroll
        for (int i = 0; i < 4; i++) {
            int k = k0 + ty + i * 8;
            int n = n0 + tx;
            tile[ty + i * 8][tx] = (n < CDIM) ? W[(size_t)k * CDIM + n] : 0.0f;
        }
        __syncthreads();
        #pragma unroll
        for (int i = 0; i < 4; i++) {
            int n = n0 + ty + i * 8;
            int k = k0 + tx;
            Bt[(size_t)n * DDIM + k] = f2bf(tile[tx][ty + i * 8]);
        }
    }
}

// ---- GEMM body: 128x128 tile, BK=64 ----
// A fragments load DIRECT from global (bf16, L1/L2-cached, no LDS round-trip).
// B staged via global_load_lds into a double buffer with ONE barrier per iter:
//   barrier (drains tile-i DMA issued a full compute phase ago) -> issue tile
//   i+1 DMA into the other buffer -> compute tile i. Issue-early/drain-late.
__device__ __forceinline__ void gemm_body(
    const unsigned short* __restrict__ A,
    const unsigned short* __restrict__ Bt,
    float* __restrict__ C,
    int mBase, int nBase, int kBase, int kIters,
    unsigned short* Bs)                    // 2 x 128 x BK bf16 (32 KiB)
{
    const int t    = threadIdx.x;
    const int wave = t >> 6;
    const int lane = t & 63;
    const int wm   = wave & 1;
    const int wn   = wave >> 1;
    const int quad = lane >> 4;
    const int l16  = lane & 15;

    floatx4 acc[4][4] = {};

    // B staging: linear layout (R2 style), 4 rounds of 32 rows
    const int byteoff = t * 16;
    const int rowB    = byteoff >> 7;
    const int colb    = byteoff & 127;
    const char* Bg = (const char*)Bt + ((size_t)(nBase + rowB) * DDIM + kBase) * 2 + colb;
    char* Dst0 = (char*)Bs + byteoff;
    char* Dst1 = (char*)Bs + 16384 + byteoff;

    // A direct: per-lane row base (row = mBase + wm*64 + l16, k chunk = quad*8)
    const unsigned short* Ab = A + (size_t)(mBase + wm * 64 + l16) * DDIM + kBase + quad * 8;

    // prologue: tile 0 -> buf0
    #pragma unroll
    for (int r = 0; r < 4; r++)
        async_copy16(Bg + (size_t)r * 32 * DDIM * 2, Dst0 + r * 4096);

    for (int i = 0; i < kIters; i++) {
        __syncthreads();   // lgkm+vm drain: tile-i DMA (issued one full phase ago)

        if (i + 1 < kIters) {
            const char* bnext = Bg + (size_t)(i + 1) * BK * 2;
            char* dst = ((i + 1) & 1) ? Dst1 : Dst0;
            #pragma unroll
            for (int r = 0; r < 4; r++)
                async_copy16(bnext + (size_t)r * 32 * DDIM * 2, dst + r * 4096);
        }

        const unsigned short* Bcur = Bs + ((i & 1) ? 8192 : 0);
        const unsigned short* Ai   = Ab + i * BK;

        #pragma unroll
        for (int ks = 0; ks < 2; ks++) {
            short8 af[4], bfr[4];
            #pragma unroll
            for (int mi = 0; mi < 4; mi++)
                af[mi] = *(const short8*)(Ai + (size_t)mi * 16 * DDIM + ks * 32);
            #pragma unroll
            for (int ni = 0; ni < 4; ni++)
                bfr[ni] = *(const short8*)(Bcur + (wn * 64 + ni * 16 + l16) * BK + ks * 32 + quad * 8);
            #pragma unroll
            for (int mi = 0; mi < 4; mi++)
                #pragma unroll
                for (int ni = 0; ni < 4; ni++)
                    acc[mi][ni] = __builtin_amdgcn_mfma_f32_16x16x32_bf16(
                        af[mi], bfr[ni], acc[mi][ni], 0, 0, 0);
        }
    }

    // C/D layout: col=lane&15, row=quad*4+reg
    #pragma unroll
    for (int mi = 0; mi < 4; mi++) {
        int row0 = mBase + wm * 64 + mi * 16 + quad * 4;
        #pragma unroll
        for (int ni = 0; ni < 4; ni++) {
            int col = nBase + wn * 64 + ni * 16 + l16;
            if (col < CDIM) {
                #pragma unroll
                for (int rg = 0; rg < 4; rg++)
                    C[(size_t)(row0 + rg) * CDIM + col] = acc[mi][ni][rg];
            }
        }
    }
}

// ---- split-K GEMM: grid 1024, XCD-swizzled; z=0 -> C0, z=1 -> C1 ----
__global__ __launch_bounds__(256, 4) void gemm_splitk_kernel(
    const unsigned short* __restrict__ A,
    const unsigned short* __restrict__ Bt,
    float* __restrict__ C0, float* __restrict__ C1)
{
    __shared__ unsigned short Bs[2 * 128 * BK];

    const int L   = blockIdx.x;          // 0..1023
    const int xcd = L & 7;
    const int s   = L >> 3;              // 0..127
    const int mz  = xcd * 16 + (s >> 3); // 0..127
    const int n_t = s & 7;
    const int m_t = mz >> 1;             // 0..63
    const int z   = mz & 1;

    float* C = z ? C1 : C0;
    gemm_body(A, Bt, C, m_t * 128, n_t * 128, z * (DDIM / 2), (DDIM / 2) / BK, Bs);
}

// ---- single-K fallback: grid 512 ----
__global__ __launch_bounds__(256, 4) void gemm_single_kernel(
    const unsigned short* __restrict__ A,
    const unsigned short* __restrict__ Bt,
    float* __restrict__ C0)
{
    __shared__ unsigned short Bs[2 * 128 * BK];

    const int L   = blockIdx.x;          // 0..511
    const int xcd = L & 7;
    const int s   = L >> 3;              // 0..63
    const int m_t = xcd * 8 + (s >> 3);
    const int n_t = s & 7;

    gemm_body(A, Bt, C0, m_t * 128, n_t * 128, 0, DDIM / BK, Bs);
}

// ---- bias + LOO-logsumexp transform; optionally sums the split-K partial ----
__global__ __launch_bounds__(256) void lse_kernel(
    float* __restrict__ C, const float* C1,
    const float* __restrict__ bias, int split)
{
    const int row = blockIdx.x;
    const int t   = threadIdx.x;
    __shared__ float red[8];

    const bool valid = t < (CDIM / 4);   // 250 threads x 4 cols
    const int c0 = t * 4;

    float4 v = make_float4(-INFINITY, -INFINITY, -INFINITY, -INFINITY);
    float4 e = make_float4(0.f, 0.f, 0.f, 0.f);
    if (valid) {
        v = *(const float4*)(C + (size_t)row * CDIM + c0);
        if (split) {
            float4 p = *(const float4*)(C1 + (size_t)row * CDIM + c0);
            v.x += p.x; v.y += p.y; v.z += p.z; v.w += p.w;
        }
        float4 bb = *(const float4*)(bias + c0);
        v.x += bb.x; v.y += bb.y; v.z += bb.z; v.w += bb.w;
    }

    float m = fmaxf(fmaxf(v.x, v.y), fmaxf(v.z, v.w));
    #pragma unroll
    for (int off = 32; off > 0; off >>= 1)
        m = fmaxf(m, __shfl_down(m, off, 64));
    const int wave = t >> 6;
    if ((t & 63) == 0) red[wave] = m;
    __syncthreads();
    if (t == 0) red[4] = fmaxf(fmaxf(red[0], red[1]), fmaxf(red[2], red[3]));
    __syncthreads();
    const float M = red[4];

    float s = 0.f;
    if (valid) {
        e.x = expf(v.x - M); e.y = expf(v.y - M);
        e.z = expf(v.z - M); e.w = expf(v.w - M);
        s = e.x + e.y + e.z + e.w;
    }
    #pragma unroll
    for (int off = 32; off > 0; off >>= 1)
        s += __shfl_down(s, off, 64);
    if ((t & 63) == 0) red[wave] = s;
    __syncthreads();
    if (t == 0) red[4] = red[0] + red[1] + red[2] + red[3];
    __syncthreads();
    const float S    = red[4];
    const float lse  = M + logf(S);
    const float invS = 1.0f / S;

    if (valid) {
        float4 o;
        o.x = (v.x - lse) - log1pf(-e.x * invS);
        o.y = (v.y - lse) - log1pf(-e.y * invS);
        o.z = (v.z - lse) - log1pf(-e.z * invS);
        o.w = (v.w - lse) - log1pf(-e.w * invS);
        *(float4*)(C + (size_t)row * CDIM + c0) = o;
    }
}

extern "C" void kernel_launch(void* const* d_in, const int* in_sizes, int n_in,
                              void* d_out, int out_size, void* d_ws, size_t ws_size,
                              hipStream_t stream) {
    const float* x = (const float*)d_in[0];   // [8192, 2048]
    const float* W = (const float*)d_in[1];   // [2048, 1000]
    const float* b = (const float*)d_in[2];   // [1000]
    float* out = (float*)d_out;               // [8192, 1000]

    unsigned short* xb = (unsigned short*)d_ws;
    unsigned short* Bt = xb + (size_t)BDIM * DDIM;
    float* C1 = (float*)((char*)d_ws + WS_C1_OFFSET);
    const bool splitk = ws_size >= WS_NEED;   // constant across calls

    // 1) fused x->bf16 + W->Bt (16384 + 2048 blocks)
    cvt_kernel<<<18432, 256, 0, stream>>>(x, xb, W, Bt);

    // 2) GEMM
    if (splitk) {
        gemm_splitk_kernel<<<1024, 256, 0, stream>>>(xb, Bt, out, C1);
        lse_kernel<<<BDIM, 256, 0, stream>>>(out, C1, b, 1);
    } else {
        gemm_single_kernel<<<512, 256, 0, stream>>>(xb, Bt, out);
        lse_kernel<<<BDIM, 256, 0, stream>>>(out, nullptr, b, 0);
    }
}

// Round 6
// 215.618 us; speedup vs baseline: 1.0013x; 1.0013x over previous
//
#include <hip/hip_runtime.h>
#include <hip/hip_bf16.h>
#include <math.h>

#define BDIM 8192
#define DDIM 2048
#define CDIM 1000
#define NPAD 1024
#define BK   32

// ws layout (bytes): xb bf16 [8192*2048] = 33554432 ; Bt bf16 [1024*2048] = 4194304 ;
// C1 fp32 partial [8192*1000] = 32768000 @ offset 37748736 ; total 70516736
#define WS_C1_OFFSET  37748736ULL
#define WS_NEED       70516736ULL

typedef __attribute__((ext_vector_type(8))) short short8;
typedef __attribute__((ext_vector_type(4))) float floatx4;

__device__ __forceinline__ unsigned short f2bf(float f) {
    union { float f; unsigned u; } a; a.f = f;
    unsigned u = a.u;
    u = (u + 0x7fff + ((u >> 16) & 1)) >> 16;   // RNE, finite inputs
    return (unsigned short)u;
}

__device__ __forceinline__ void async_copy16(const void* gp, void* lp) {
    __builtin_amdgcn_global_load_lds(
        (const __attribute__((address_space(1))) void*)gp,
        (__attribute__((address_space(3))) void*)lp,
        16, 0, 0);
}

// ---- kernel 1: fused x->bf16 (blocks 0..16383) and W->Bt transpose (blocks 16384..18431) ----
__global__ __launch_bounds__(256) void cvt_kernel(
    const float* __restrict__ x, unsigned short* __restrict__ xb,
    const float* __restrict__ W, unsigned short* __restrict__ Bt)
{
    const int blk = blockIdx.x;
    const int t   = threadIdx.x;
    if (blk < 16384) {
        int i = blk * 256 + t;
        float4 v = ((const float4*)x)[i];
        ushort4 o;
        o.x = f2bf(v.x); o.y = f2bf(v.y); o.z = f2bf(v.z); o.w = f2bf(v.w);
        ((ushort4*)xb)[i] = o;
    } else {
        __shared__ float tile[32][33];
        const int b2 = blk - 16384;          // 64 k-tiles x 32 n-tiles
        const int k0 = (b2 & 63) * 32;
        const int n0 = (b2 >> 6) * 32;
        const int tx = t & 31, ty = t >> 5;  // 32 x 8
        #pragma unroll
        for (int i = 0; i < 4; i++) {
            int k = k0 + ty + i * 8;
            int n = n0 + tx;
            tile[ty + i * 8][tx] = (n < CDIM) ? W[(size_t)k * CDIM + n] : 0.0f;
        }
        __syncthreads();
        #pragma unroll
        for (int i = 0; i < 4; i++) {
            int n = n0 + ty + i * 8;
            int k = k0 + tx;
            Bt[(size_t)n * DDIM + k] = f2bf(tile[tx][ty + i * 8]);
        }
    }
}

// ---- GEMM body: 128x128 tile, BK=32 ----
// A: register prefetch one full iteration ahead (issued with B-DMA, drained by
//    the NEXT barrier -> >= one compute phase of latency hiding; 2nd wave of a
//    wm-pair hits L1).
// B: global_load_lds double-buffer, ONE barrier per iter. Barrier at iter top
//    drains DMA(i) issued one full compute phase ago; DMA(i+1) issued right
//    after. 8KB drained per barrier.
__device__ __forceinline__ void gemm_body(
    const unsigned short* __restrict__ A,
    const unsigned short* __restrict__ Bt,
    float* __restrict__ C,
    int mBase, int nBase, int kBase, int kIters,
    unsigned short* Bs)                    // 2 x 128 x BK bf16 (16 KiB)
{
    const int t    = threadIdx.x;
    const int wave = t >> 6;
    const int lane = t & 63;
    const int wm   = wave & 1;
    const int wn   = wave >> 1;
    const int quad = lane >> 4;
    const int l16  = lane & 15;

    floatx4 acc[4][4] = {};

    // B staging: 8KB/tile, 2 rounds of 64 rows; thread t -> row t>>2, 16B chunk t&3
    const char* Bg0 = (const char*)Bt
        + ((size_t)(nBase + (t >> 2)) * DDIM + kBase) * 2 + (t & 3) * 16;
    char* Dst0 = (char*)Bs + t * 16;       // + buf*8192 + r*4096

    // A direct-from-global fragment base: row = mBase + wm*64 + l16, k chunk quad*8
    const unsigned short* Ap = A + (size_t)(mBase + wm * 64 + l16) * DDIM + kBase + quad * 8;

    short8 afbuf[2][4];

    // prologue: B tile 0 -> buf0 ; A frags iter 0
    #pragma unroll
    for (int r = 0; r < 2; r++)
        async_copy16(Bg0 + (size_t)r * 64 * DDIM * 2, Dst0 + r * 4096);
    #pragma unroll
    for (int mi = 0; mi < 4; mi++)
        afbuf[0][mi] = *(const short8*)(Ap + (size_t)mi * 16 * DDIM);

    #pragma unroll 2
    for (int i = 0; i < kIters; i++) {
        __syncthreads();   // drains B-DMA(i) + A-prefetch(i) (issued one phase ago)

        if (i + 1 < kIters) {
            const char* bnext = Bg0 + (size_t)(i + 1) * BK * 2;
            char* dst = Dst0 + ((i + 1) & 1) * 8192;
            #pragma unroll
            for (int r = 0; r < 2; r++)
                async_copy16(bnext + (size_t)r * 64 * DDIM * 2, dst + r * 4096);
            const unsigned short* An = Ap + (size_t)(i + 1) * BK;
            #pragma unroll
            for (int mi = 0; mi < 4; mi++)
                afbuf[(i + 1) & 1][mi] = *(const short8*)(An + (size_t)mi * 16 * DDIM);
        }

        const unsigned short* Bcur = Bs + (i & 1) * 4096;   // ushort units
        short8 bfr[4];
        #pragma unroll
        for (int ni = 0; ni < 4; ni++)
            bfr[ni] = *(const short8*)(Bcur + (wn * 64 + ni * 16 + l16) * BK + quad * 8);
        #pragma unroll
        for (int mi = 0; mi < 4; mi++)
            #pragma unroll
            for (int ni = 0; ni < 4; ni++)
                acc[mi][ni] = __builtin_amdgcn_mfma_f32_16x16x32_bf16(
                    afbuf[i & 1][mi], bfr[ni], acc[mi][ni], 0, 0, 0);
    }

    // C/D layout: col=lane&15, row=quad*4+reg
    #pragma unroll
    for (int mi = 0; mi < 4; mi++) {
        int row0 = mBase + wm * 64 + mi * 16 + quad * 4;
        #pragma unroll
        for (int ni = 0; ni < 4; ni++) {
            int col = nBase + wn * 64 + ni * 16 + l16;
            if (col < CDIM) {
                #pragma unroll
                for (int rg = 0; rg < 4; rg++)
                    C[(size_t)(row0 + rg) * CDIM + col] = acc[mi][ni][rg];
            }
        }
    }
}

// ---- split-K GEMM: grid 1024, XCD-swizzled; z=0 -> C0, z=1 -> C1 ----
__global__ __launch_bounds__(256, 4) void gemm_splitk_kernel(
    const unsigned short* __restrict__ A,
    const unsigned short* __restrict__ Bt,
    float* __restrict__ C0, float* __restrict__ C1)
{
    __shared__ unsigned short Bs[2 * 128 * BK];

    const int L   = blockIdx.x;          // 0..1023
    const int xcd = L & 7;
    const int s   = L >> 3;              // 0..127
    const int mz  = xcd * 16 + (s >> 3); // 0..127
    const int n_t = s & 7;
    const int m_t = mz >> 1;             // 0..63
    const int z   = mz & 1;

    float* C = z ? C1 : C0;
    gemm_body(A, Bt, C, m_t * 128, n_t * 128, z * (DDIM / 2), (DDIM / 2) / BK, Bs);
}

// ---- single-K fallback: grid 512 ----
__global__ __launch_bounds__(256, 4) void gemm_single_kernel(
    const unsigned short* __restrict__ A,
    const unsigned short* __restrict__ Bt,
    float* __restrict__ C0)
{
    __shared__ unsigned short Bs[2 * 128 * BK];

    const int L   = blockIdx.x;          // 0..511
    const int xcd = L & 7;
    const int s   = L >> 3;              // 0..63
    const int m_t = xcd * 8 + (s >> 3);
    const int n_t = s & 7;

    gemm_body(A, Bt, C0, m_t * 128, n_t * 128, 0, DDIM / BK, Bs);
}

// ---- bias + LOO-logsumexp transform; optionally sums the split-K partial ----
__global__ __launch_bounds__(256) void lse_kernel(
    float* __restrict__ C, const float* C1,
    const float* __restrict__ bias, int split)
{
    const int row = blockIdx.x;
    const int t   = threadIdx.x;
    __shared__ float red[8];

    const bool valid = t < (CDIM / 4);   // 250 threads x 4 cols
    const int c0 = t * 4;

    float4 v = make_float4(-INFINITY, -INFINITY, -INFINITY, -INFINITY);
    float4 e = make_float4(0.f, 0.f, 0.f, 0.f);
    if (valid) {
        v = *(const float4*)(C + (size_t)row * CDIM + c0);
        if (split) {
            float4 p = *(const float4*)(C1 + (size_t)row * CDIM + c0);
            v.x += p.x; v.y += p.y; v.z += p.z; v.w += p.w;
        }
        float4 bb = *(const float4*)(bias + c0);
        v.x += bb.x; v.y += bb.y; v.z += bb.z; v.w += bb.w;
    }

    float m = fmaxf(fmaxf(v.x, v.y), fmaxf(v.z, v.w));
    #pragma unroll
    for (int off = 32; off > 0; off >>= 1)
        m = fmaxf(m, __shfl_down(m, off, 64));
    const int wave = t >> 6;
    if ((t & 63) == 0) red[wave] = m;
    __syncthreads();
    if (t == 0) red[4] = fmaxf(fmaxf(red[0], red[1]), fmaxf(red[2], red[3]));
    __syncthreads();
    const float M = red[4];

    float s = 0.f;
    if (valid) {
        e.x = expf(v.x - M); e.y = expf(v.y - M);
        e.z = expf(v.z - M); e.w = expf(v.w - M);
        s = e.x + e.y + e.z + e.w;
    }
    #pragma unroll
    for (int off = 32; off > 0; off >>= 1)
        s += __shfl_down(s, off, 64);
    if ((t & 63) == 0) red[wave] = s;
    __syncthreads();
    if (t == 0) red[4] = red[0] + red[1] + red[2] + red[3];
    __syncthreads();
    const float S    = red[4];
    const float lse  = M + logf(S);
    const float invS = 1.0f / S;

    if (valid) {
        float4 o;
        o.x = (v.x - lse) - log1pf(-e.x * invS);
        o.y = (v.y - lse) - log1pf(-e.y * invS);
        o.z = (v.z - lse) - log1pf(-e.z * invS);
        o.w = (v.w - lse) - log1pf(-e.w * invS);
        *(float4*)(C + (size_t)row * CDIM + c0) = o;
    }
}

extern "C" void kernel_launch(void* const* d_in, const int* in_sizes, int n_in,
                              void* d_out, int out_size, void* d_ws, size_t ws_size,
                              hipStream_t stream) {
    const float* x = (const float*)d_in[0];   // [8192, 2048]
    const float* W = (const float*)d_in[1];   // [2048, 1000]
    const float* b = (const float*)d_in[2];   // [1000]
    float* out = (float*)d_out;               // [8192, 1000]

    unsigned short* xb = (unsigned short*)d_ws;
    unsigned short* Bt = xb + (size_t)BDIM * DDIM;
    float* C1 = (float*)((char*)d_ws + WS_C1_OFFSET);
    const bool splitk = ws_size >= WS_NEED;   // constant across calls

    // 1) fused x->bf16 + W->Bt (16384 + 2048 blocks)
    cvt_kernel<<<18432, 256, 0, stream>>>(x, xb, W, Bt);

    // 2) GEMM
    if (splitk) {
        gemm_splitk_kernel<<<1024, 256, 0, stream>>>(xb, Bt, out, C1);
        lse_kernel<<<BDIM, 256, 0, stream>>>(out, C1, b, 1);
    } else {
        gemm_single_kernel<<<512, 256, 0, stream>>>(xb, Bt, out);
        lse_kernel<<<BDIM, 256, 0, stream>>>(out, nullptr, b, 0);
    }
}

// Round 7
// 183.962 us; speedup vs baseline: 1.1736x; 1.1721x over previous
//
#include <hip/hip_runtime.h>
#include <hip/hip_bf16.h>
#include <math.h>

#define BDIM 8192
#define DDIM 2048
#define CDIM 1000
#define NPAD 1024
#define BK   64

// ws layout (bytes): xb bf16 [8192*2048] = 33554432 ; Bt bf16 [1024*2048] = 4194304 ;
// C1 fp32 partial [8192*1000] = 32768000 @ offset 37748736 ; total 70516736
#define WS_C1_OFFSET  37748736ULL
#define WS_NEED       70516736ULL

typedef __attribute__((ext_vector_type(8))) short short8;
typedef __attribute__((ext_vector_type(4))) float floatx4;

__device__ __forceinline__ unsigned short f2bf(float f) {
    union { float f; unsigned u; } a; a.f = f;
    unsigned u = a.u;
    u = (u + 0x7fff + ((u >> 16) & 1)) >> 16;   // RNE, finite inputs
    return (unsigned short)u;
}

__device__ __forceinline__ void async_copy16(const void* gp, void* lp) {
    __builtin_amdgcn_global_load_lds(
        (const __attribute__((address_space(1))) void*)gp,
        (__attribute__((address_space(3))) void*)lp,
        16, 0, 0);
}

// ---- kernel 1: fused x->bf16 (blocks 0..16383) and W->Bt transpose (blocks 16384..18431) ----
__global__ __launch_bounds__(256) void cvt_kernel(
    const float* __restrict__ x, unsigned short* __restrict__ xb,
    const float* __restrict__ W, unsigned short* __restrict__ Bt)
{
    const int blk = blockIdx.x;
    const int t   = threadIdx.x;
    if (blk < 16384) {
        int i = blk * 256 + t;
        float4 v = ((const float4*)x)[i];
        ushort4 o;
        o.x = f2bf(v.x); o.y = f2bf(v.y); o.z = f2bf(v.z); o.w = f2bf(v.w);
        ((ushort4*)xb)[i] = o;
    } else {
        __shared__ float tile[32][33];
        const int b2 = blk - 16384;          // 64 k-tiles x 32 n-tiles
        const int k0 = (b2 & 63) * 32;
        const int n0 = (b2 >> 6) * 32;
        const int tx = t & 31, ty = t >> 5;  // 32 x 8
        #pragma unroll
        for (int i = 0; i < 4; i++) {
            int k = k0 + ty + i * 8;
            int n = n0 + tx;
            tile[ty + i * 8][tx] = (n < CDIM) ? W[(size_t)k * CDIM + n] : 0.0f;
        }
        __syncthreads();
        #pragma unroll
        for (int i = 0; i < 4; i++) {
            int n = n0 + ty + i * 8;
            int k = k0 + tx;
            Bt[(size_t)n * DDIM + k] = f2bf(tile[tx][ty + i * 8]);
        }
    }
}

// ---- GEMM body: R2 structure + XOR-swizzled LDS chunk placement ----
// LDS slot for (row R, 16B chunk c) holds global chunk (c ^ (R&7)).
// Staging lanes still cover whole 128B row segments (lane<->chunk permuted
// within a row only -> DMA coalescing preserved, unlike R4's row scatter).
// Fragment ds_read_b128 then spreads the 16 l16-lanes over all 8 bank
// groups (Rm&7 = l16&7) -> 2 lanes/group = conflict-free (m136).
__device__ __forceinline__ void gemm_body(
    const unsigned short* __restrict__ A,
    const unsigned short* __restrict__ Bt,
    float* __restrict__ C,
    int mBase, int nBase, int kBase, int kIters,
    unsigned short* As, unsigned short* Bs)
{
    const int t    = threadIdx.x;
    const int wave = t >> 6;
    const int lane = t & 63;
    const int wm   = wave & 1;
    const int wn   = wave >> 1;
    const int quad = lane >> 4;
    const int l16  = lane & 15;

    floatx4 acc[4][4] = {};

    // staging: thread t -> dst slot (rowA = t>>3, chunk c = t&7); fetch the
    // global chunk that belongs there: c' = c ^ (rowA&7). (32r keeps R&7.)
    const int rowA = t >> 3;
    const int csw  = ((t & 7) ^ (rowA & 7)) * 16;   // swizzled source byte col
    const char* Ag = (const char*)A  + ((size_t)(mBase + rowA) * DDIM + kBase) * 2 + csw;
    const char* Bg = (const char*)Bt + ((size_t)(nBase + rowA) * DDIM + kBase) * 2 + csw;
    char* AsDst = (char*)As + t * 16;
    char* BsDst = (char*)Bs + t * 16;

    // fragment-read XOR term: chunk cf = ks*4+quad, swizzled by (Rm&7)=(l16&7)
    const int xorb0 = ((0 * 4 + quad) ^ (l16 & 7)) * 8;   // ks=0, ushort units
    const int xorb1 = ((1 * 4 + quad) ^ (l16 & 7)) * 8;   // ks=1

    for (int kt = 0; kt < kIters * BK; kt += BK) {
        const char* a = Ag + kt * 2;
        const char* b = Bg + kt * 2;
        #pragma unroll
        for (int r = 0; r < 4; r++) {
            async_copy16(a + (size_t)r * 32 * DDIM * 2, AsDst + r * 4096);
            async_copy16(b + (size_t)r * 32 * DDIM * 2, BsDst + r * 4096);
        }
        __syncthreads();

        #pragma unroll
        for (int ks = 0; ks < 2; ks++) {
            const int xorb = ks ? xorb1 : xorb0;
            short8 af[4], bfr[4];
            #pragma unroll
            for (int mi = 0; mi < 4; mi++)
                af[mi] = *(const short8*)(As + (wm * 64 + mi * 16 + l16) * BK + xorb);
            #pragma unroll
            for (int ni = 0; ni < 4; ni++)
                bfr[ni] = *(const short8*)(Bs + (wn * 64 + ni * 16 + l16) * BK + xorb);
            #pragma unroll
            for (int mi = 0; mi < 4; mi++)
                #pragma unroll
                for (int ni = 0; ni < 4; ni++)
                    acc[mi][ni] = __builtin_amdgcn_mfma_f32_16x16x32_bf16(
                        af[mi], bfr[ni], acc[mi][ni], 0, 0, 0);
        }
        __syncthreads();
    }

    // C/D layout: col=lane&15, row=quad*4+reg
    #pragma unroll
    for (int mi = 0; mi < 4; mi++) {
        int row0 = mBase + wm * 64 + mi * 16 + quad * 4;
        #pragma unroll
        for (int ni = 0; ni < 4; ni++) {
            int col = nBase + wn * 64 + ni * 16 + l16;
            if (col < CDIM) {
                #pragma unroll
                for (int rg = 0; rg < 4; rg++)
                    C[(size_t)(row0 + rg) * CDIM + col] = acc[mi][ni][rg];
            }
        }
    }
}

// ---- split-K GEMM: grid 1024, XCD-swizzled; z=0 -> C0, z=1 -> C1 ----
__global__ __launch_bounds__(256, 4) void gemm_splitk_kernel(
    const unsigned short* __restrict__ A,
    const unsigned short* __restrict__ Bt,
    float* __restrict__ C0, float* __restrict__ C1)
{
    __shared__ unsigned short As[128 * BK];
    __shared__ unsigned short Bs[128 * BK];

    const int L   = blockIdx.x;          // 0..1023
    const int xcd = L & 7;
    const int s   = L >> 3;              // 0..127
    const int mz  = xcd * 16 + (s >> 3); // 0..127
    const int n_t = s & 7;
    const int m_t = mz >> 1;             // 0..63
    const int z   = mz & 1;

    float* C = z ? C1 : C0;
    gemm_body(A, Bt, C, m_t * 128, n_t * 128, z * (DDIM / 2), (DDIM / 2) / BK, As, Bs);
}

// ---- single-K fallback: grid 512 ----
__global__ __launch_bounds__(256, 2) void gemm_single_kernel(
    const unsigned short* __restrict__ A,
    const unsigned short* __restrict__ Bt,
    float* __restrict__ C0)
{
    __shared__ unsigned short As[128 * BK];
    __shared__ unsigned short Bs[128 * BK];

    const int L   = blockIdx.x;          // 0..511
    const int xcd = L & 7;
    const int s   = L >> 3;              // 0..63
    const int m_t = xcd * 8 + (s >> 3);
    const int n_t = s & 7;

    gemm_body(A, Bt, C0, m_t * 128, n_t * 128, 0, DDIM / BK, As, Bs);
}

// ---- bias + LOO-logsumexp transform; optionally sums the split-K partial ----
__global__ __launch_bounds__(256) void lse_kernel(
    float* __restrict__ C, const float* C1,
    const float* __restrict__ bias, int split)
{
    const int row = blockIdx.x;
    const int t   = threadIdx.x;
    __shared__ float red[8];

    const bool valid = t < (CDIM / 4);   // 250 threads x 4 cols
    const int c0 = t * 4;

    float4 v = make_float4(-INFINITY, -INFINITY, -INFINITY, -INFINITY);
    float4 e = make_float4(0.f, 0.f, 0.f, 0.f);
    if (valid) {
        v = *(const float4*)(C + (size_t)row * CDIM + c0);
        if (split) {
            float4 p = *(const float4*)(C1 + (size_t)row * CDIM + c0);
            v.x += p.x; v.y += p.y; v.z += p.z; v.w += p.w;
        }
        float4 bb = *(const float4*)(bias + c0);
        v.x += bb.x; v.y += bb.y; v.z += bb.z; v.w += bb.w;
    }

    float m = fmaxf(fmaxf(v.x, v.y), fmaxf(v.z, v.w));
    #pragma unroll
    for (int off = 32; off > 0; off >>= 1)
        m = fmaxf(m, __shfl_down(m, off, 64));
    const int wave = t >> 6;
    if ((t & 63) == 0) red[wave] = m;
    __syncthreads();
    if (t == 0) red[4] = fmaxf(fmaxf(red[0], red[1]), fmaxf(red[2], red[3]));
    __syncthreads();
    const float M = red[4];

    float s = 0.f;
    if (valid) {
        e.x = expf(v.x - M); e.y = expf(v.y - M);
        e.z = expf(v.z - M); e.w = expf(v.w - M);
        s = e.x + e.y + e.z + e.w;
    }
    #pragma unroll
    for (int off = 32; off > 0; off >>= 1)
        s += __shfl_down(s, off, 64);
    if ((t & 63) == 0) red[wave] = s;
    __syncthreads();
    if (t == 0) red[4] = red[0] + red[1] + red[2] + red[3];
    __syncthreads();
    const float S    = red[4];
    const float lse  = M + logf(S);
    const float invS = 1.0f / S;

    if (valid) {
        float4 o;
        o.x = (v.x - lse) - log1pf(-e.x * invS);
        o.y = (v.y - lse) - log1pf(-e.y * invS);
        o.z = (v.z - lse) - log1pf(-e.z * invS);
        o.w = (v.w - lse) - log1pf(-e.w * invS);
        *(float4*)(C + (size_t)row * CDIM + c0) = o;
    }
}

extern "C" void kernel_launch(void* const* d_in, const int* in_sizes, int n_in,
                              void* d_out, int out_size, void* d_ws, size_t ws_size,
                              hipStream_t stream) {
    const float* x = (const float*)d_in[0];   // [8192, 2048]
    const float* W = (const float*)d_in[1];   // [2048, 1000]
    const float* b = (const float*)d_in[2];   // [1000]
    float* out = (float*)d_out;               // [8192, 1000]

    unsigned short* xb = (unsigned short*)d_ws;
    unsigned short* Bt = xb + (size_t)BDIM * DDIM;
    float* C1 = (float*)((char*)d_ws + WS_C1_OFFSET);
    const bool splitk = ws_size >= WS_NEED;   // constant across calls

    // 1) fused x->bf16 + W->Bt (16384 + 2048 blocks)
    cvt_kernel<<<18432, 256, 0, stream>>>(x, xb, W, Bt);

    // 2) GEMM
    if (splitk) {
        gemm_splitk_kernel<<<1024, 256, 0, stream>>>(xb, Bt, out, C1);
        lse_kernel<<<BDIM, 256, 0, stream>>>(out, C1, b, 1);
    } else {
        gemm_single_kernel<<<512, 256, 0, stream>>>(xb, Bt, out);
        lse_kernel<<<BDIM, 256, 0, stream>>>(out, nullptr, b, 0);
    }
}

// Round 8
// 180.108 us; speedup vs baseline: 1.1987x; 1.0214x over previous
//
#include <hip/hip_runtime.h>
#include <hip/hip_bf16.h>
#include <math.h>

#define BDIM 8192
#define DDIM 2048
#define CDIM 1000
#define NPAD 1024
#define BK   64

// ws layout (bytes):
//   xb bf16 [8192*2048] = 33554432 @ 0
//   Bt bf16 [1024*2048] =  4194304 @ 33554432
//   P0 bf16 [8192*1000] = 16384000 @ 37748736   (split-K partial, k-half 0)
//   P1 bf16 [8192*1000] = 16384000 @ 54132736   (split-K partial, k-half 1)
// total = 70516736 (same as prior rounds' proven-fitting WS_NEED)
#define WS_BT_OFFSET  33554432ULL
#define WS_P0_OFFSET  37748736ULL
#define WS_P1_OFFSET  54132736ULL
#define WS_NEED       70516736ULL

typedef __attribute__((ext_vector_type(8))) short short8;
typedef __attribute__((ext_vector_type(4))) float floatx4;

__device__ __forceinline__ unsigned short f2bf(float f) {
    union { float f; unsigned u; } a; a.f = f;
    unsigned u = a.u;
    u = (u + 0x7fff + ((u >> 16) & 1)) >> 16;   // RNE, finite inputs
    return (unsigned short)u;
}

__device__ __forceinline__ float bf2f(unsigned short h) {
    union { unsigned u; float f; } a; a.u = ((unsigned)h) << 16;
    return a.f;
}

__device__ __forceinline__ void async_copy16(const void* gp, void* lp) {
    __builtin_amdgcn_global_load_lds(
        (const __attribute__((address_space(1))) void*)gp,
        (__attribute__((address_space(3))) void*)lp,
        16, 0, 0);
}

// ---- kernel 1: fused x->bf16 (blocks 0..16383) and W->Bt transpose (blocks 16384..18431) ----
__global__ __launch_bounds__(256) void cvt_kernel(
    const float* __restrict__ x, unsigned short* __restrict__ xb,
    const float* __restrict__ W, unsigned short* __restrict__ Bt)
{
    const int blk = blockIdx.x;
    const int t   = threadIdx.x;
    if (blk < 16384) {
        int i = blk * 256 + t;
        float4 v = ((const float4*)x)[i];
        ushort4 o;
        o.x = f2bf(v.x); o.y = f2bf(v.y); o.z = f2bf(v.z); o.w = f2bf(v.w);
        ((ushort4*)xb)[i] = o;
    } else {
        __shared__ float tile[32][33];
        const int b2 = blk - 16384;          // 64 k-tiles x 32 n-tiles
        const int k0 = (b2 & 63) * 32;
        const int n0 = (b2 >> 6) * 32;
        const int tx = t & 31, ty = t >> 5;  // 32 x 8
        #pragma unroll
        for (int i = 0; i < 4; i++) {
            int k = k0 + ty + i * 8;
            int n = n0 + tx;
            tile[ty + i * 8][tx] = (n < CDIM) ? W[(size_t)k * CDIM + n] : 0.0f;
        }
        __syncthreads();
        #pragma unroll
        for (int i = 0; i < 4; i++) {
            int n = n0 + ty + i * 8;
            int k = k0 + tx;
            Bt[(size_t)n * DDIM + k] = f2bf(tile[tx][ty + i * 8]);
        }
    }
}

// ---- GEMM body: R7 structure (XOR-swizzled LDS, zero bank conflicts) ----
// BF16OUT: store partials as bf16 (split-K path); else fp32 (fallback).
template <bool BF16OUT>
__device__ __forceinline__ void gemm_body(
    const unsigned short* __restrict__ A,
    const unsigned short* __restrict__ Bt,
    void* __restrict__ Cv,
    int mBase, int nBase, int kBase, int kIters,
    unsigned short* As, unsigned short* Bs)
{
    const int t    = threadIdx.x;
    const int wave = t >> 6;
    const int lane = t & 63;
    const int wm   = wave & 1;
    const int wn   = wave >> 1;
    const int quad = lane >> 4;
    const int l16  = lane & 15;

    floatx4 acc[4][4] = {};

    // staging: thread t -> dst slot (rowA = t>>3, chunk c = t&7); fetch the
    // global chunk that belongs there: c' = c ^ (rowA&7). (32r keeps R&7.)
    const int rowA = t >> 3;
    const int csw  = ((t & 7) ^ (rowA & 7)) * 16;   // swizzled source byte col
    const char* Ag = (const char*)A  + ((size_t)(mBase + rowA) * DDIM + kBase) * 2 + csw;
    const char* Bg = (const char*)Bt + ((size_t)(nBase + rowA) * DDIM + kBase) * 2 + csw;
    char* AsDst = (char*)As + t * 16;
    char* BsDst = (char*)Bs + t * 16;

    // fragment-read XOR term: chunk cf = ks*4+quad, swizzled by (Rm&7)=(l16&7)
    const int xorb0 = ((0 * 4 + quad) ^ (l16 & 7)) * 8;   // ks=0, ushort units
    const int xorb1 = ((1 * 4 + quad) ^ (l16 & 7)) * 8;   // ks=1

    for (int kt = 0; kt < kIters * BK; kt += BK) {
        const char* a = Ag + kt * 2;
        const char* b = Bg + kt * 2;
        #pragma unroll
        for (int r = 0; r < 4; r++) {
            async_copy16(a + (size_t)r * 32 * DDIM * 2, AsDst + r * 4096);
            async_copy16(b + (size_t)r * 32 * DDIM * 2, BsDst + r * 4096);
        }
        __syncthreads();

        #pragma unroll
        for (int ks = 0; ks < 2; ks++) {
            const int xorb = ks ? xorb1 : xorb0;
            short8 af[4], bfr[4];
            #pragma unroll
            for (int mi = 0; mi < 4; mi++)
                af[mi] = *(const short8*)(As + (wm * 64 + mi * 16 + l16) * BK + xorb);
            #pragma unroll
            for (int ni = 0; ni < 4; ni++)
                bfr[ni] = *(const short8*)(Bs + (wn * 64 + ni * 16 + l16) * BK + xorb);
            #pragma unroll
            for (int mi = 0; mi < 4; mi++)
                #pragma unroll
                for (int ni = 0; ni < 4; ni++)
                    acc[mi][ni] = __builtin_amdgcn_mfma_f32_16x16x32_bf16(
                        af[mi], bfr[ni], acc[mi][ni], 0, 0, 0);
        }
        __syncthreads();
    }

    // C/D layout: col=lane&15, row=quad*4+reg
    #pragma unroll
    for (int mi = 0; mi < 4; mi++) {
        int row0 = mBase + wm * 64 + mi * 16 + quad * 4;
        #pragma unroll
        for (int ni = 0; ni < 4; ni++) {
            int col = nBase + wn * 64 + ni * 16 + l16;
            if (col < CDIM) {
                #pragma unroll
                for (int rg = 0; rg < 4; rg++) {
                    if (BF16OUT)
                        ((unsigned short*)Cv)[(size_t)(row0 + rg) * CDIM + col] =
                            f2bf(acc[mi][ni][rg]);
                    else
                        ((float*)Cv)[(size_t)(row0 + rg) * CDIM + col] = acc[mi][ni][rg];
                }
            }
        }
    }
}

// ---- split-K GEMM: grid 1024, XCD-swizzled; z=0 -> P0, z=1 -> P1 (bf16) ----
__global__ __launch_bounds__(256, 4) void gemm_splitk_kernel(
    const unsigned short* __restrict__ A,
    const unsigned short* __restrict__ Bt,
    unsigned short* __restrict__ P0, unsigned short* __restrict__ P1)
{
    __shared__ unsigned short As[128 * BK];
    __shared__ unsigned short Bs[128 * BK];

    const int L   = blockIdx.x;          // 0..1023
    const int xcd = L & 7;
    const int s   = L >> 3;              // 0..127
    const int mz  = xcd * 16 + (s >> 3); // 0..127
    const int n_t = s & 7;
    const int m_t = mz >> 1;             // 0..63
    const int z   = mz & 1;

    unsigned short* P = z ? P1 : P0;
    gemm_body<true>(A, Bt, P, m_t * 128, n_t * 128, z * (DDIM / 2), (DDIM / 2) / BK, As, Bs);
}

// ---- single-K fallback: grid 512, fp32 out ----
__global__ __launch_bounds__(256, 2) void gemm_single_kernel(
    const unsigned short* __restrict__ A,
    const unsigned short* __restrict__ Bt,
    float* __restrict__ C0)
{
    __shared__ unsigned short As[128 * BK];
    __shared__ unsigned short Bs[128 * BK];

    const int L   = blockIdx.x;          // 0..511
    const int xcd = L & 7;
    const int s   = L >> 3;              // 0..63
    const int m_t = xcd * 8 + (s >> 3);
    const int n_t = s & 7;

    gemm_body<false>(A, Bt, C0, m_t * 128, n_t * 128, 0, DDIM / BK, As, Bs);
}

// ---- bias + LOO-logsumexp; split: sum two bf16 partials -> fp32 out ----
__global__ __launch_bounds__(256) void lse_kernel(
    float* __restrict__ out,
    const unsigned short* P0, const unsigned short* P1,
    const float* __restrict__ bias, int split)
{
    const int row = blockIdx.x;
    const int t   = threadIdx.x;
    __shared__ float red[8];

    const bool valid = t < (CDIM / 4);   // 250 threads x 4 cols
    const int c0 = t * 4;

    float4 v = make_float4(-INFINITY, -INFINITY, -INFINITY, -INFINITY);
    float4 e = make_float4(0.f, 0.f, 0.f, 0.f);
    if (valid) {
        if (split) {
            // byte offset (row*1000+c0)*2 = 2000*row + 8*t -> 8B aligned
            ushort4 p0 = *(const ushort4*)(P0 + (size_t)row * CDIM + c0);
            ushort4 p1 = *(const ushort4*)(P1 + (size_t)row * CDIM + c0);
            v.x = bf2f(p0.x) + bf2f(p1.x);
            v.y = bf2f(p0.y) + bf2f(p1.y);
            v.z = bf2f(p0.z) + bf2f(p1.z);
            v.w = bf2f(p0.w) + bf2f(p1.w);
        } else {
            v = *(const float4*)(out + (size_t)row * CDIM + c0);
        }
        float4 bb = *(const float4*)(bias + c0);
        v.x += bb.x; v.y += bb.y; v.z += bb.z; v.w += bb.w;
    }

    float m = fmaxf(fmaxf(v.x, v.y), fmaxf(v.z, v.w));
    #pragma unroll
    for (int off = 32; off > 0; off >>= 1)
        m = fmaxf(m, __shfl_down(m, off, 64));
    const int wave = t >> 6;
    if ((t & 63) == 0) red[wave] = m;
    __syncthreads();
    if (t == 0) red[4] = fmaxf(fmaxf(red[0], red[1]), fmaxf(red[2], red[3]));
    __syncthreads();
    const float M = red[4];

    float s = 0.f;
    if (valid) {
        e.x = expf(v.x - M); e.y = expf(v.y - M);
        e.z = expf(v.z - M); e.w = expf(v.w - M);
        s = e.x + e.y + e.z + e.w;
    }
    #pragma unroll
    for (int off = 32; off > 0; off >>= 1)
        s += __shfl_down(s, off, 64);
    if ((t & 63) == 0) red[wave] = s;
    __syncthreads();
    if (t == 0) red[4] = red[0] + red[1] + red[2] + red[3];
    __syncthreads();
    const float S    = red[4];
    const float lse  = M + logf(S);
    const float invS = 1.0f / S;

    if (valid) {
        float4 o;
        o.x = (v.x - lse) - log1pf(-e.x * invS);
        o.y = (v.y - lse) - log1pf(-e.y * invS);
        o.z = (v.z - lse) - log1pf(-e.z * invS);
        o.w = (v.w - lse) - log1pf(-e.w * invS);
        *(float4*)(out + (size_t)row * CDIM + c0) = o;
    }
}

extern "C" void kernel_launch(void* const* d_in, const int* in_sizes, int n_in,
                              void* d_out, int out_size, void* d_ws, size_t ws_size,
                              hipStream_t stream) {
    const float* x = (const float*)d_in[0];   // [8192, 2048]
    const float* W = (const float*)d_in[1];   // [2048, 1000]
    const float* b = (const float*)d_in[2];   // [1000]
    float* out = (float*)d_out;               // [8192, 1000]

    unsigned short* xb = (unsigned short*)d_ws;
    unsigned short* Bt = (unsigned short*)((char*)d_ws + WS_BT_OFFSET);
    unsigned short* P0 = (unsigned short*)((char*)d_ws + WS_P0_OFFSET);
    unsigned short* P1 = (unsigned short*)((char*)d_ws + WS_P1_OFFSET);
    const bool splitk = ws_size >= WS_NEED;   // constant across calls

    // 1) fused x->bf16 + W->Bt (16384 + 2048 blocks)
    cvt_kernel<<<18432, 256, 0, stream>>>(x, xb, W, Bt);

    // 2) GEMM + 3) LOO-LSE
    if (splitk) {
        gemm_splitk_kernel<<<1024, 256, 0, stream>>>(xb, Bt, P0, P1);
        lse_kernel<<<BDIM, 256, 0, stream>>>(out, P0, P1, b, 1);
    } else {
        gemm_single_kernel<<<512, 256, 0, stream>>>(xb, Bt, out);
        lse_kernel<<<BDIM, 256, 0, stream>>>(out, nullptr, nullptr, b, 0);
    }
}

// Round 9
// 178.787 us; speedup vs baseline: 1.2076x; 1.0074x over previous
//
#include <hip/hip_runtime.h>
#include <hip/hip_bf16.h>
#include <math.h>

#define BDIM 8192
#define DDIM 2048
#define CDIM 1000
#define NPAD 1024
#define BK   64

// ws layout (bytes):
//   xb bf16 [8192*2048] = 33554432 @ 0
//   Bt bf16 [1024*2048] =  4194304 @ 33554432
//   P0 bf16 [8192*1000] = 16384000 @ 37748736   (split-K partial, k-half 0)
//   P1 bf16 [8192*1000] = 16384000 @ 54132736   (split-K partial, k-half 1)
#define WS_BT_OFFSET  33554432ULL
#define WS_P0_OFFSET  37748736ULL
#define WS_P1_OFFSET  54132736ULL
#define WS_NEED       70516736ULL

typedef __attribute__((ext_vector_type(8))) short short8;
typedef __attribute__((ext_vector_type(4))) float floatx4;

__device__ __forceinline__ unsigned short f2bf(float f) {
    union { float f; unsigned u; } a; a.f = f;
    unsigned u = a.u;
    u = (u + 0x7fff + ((u >> 16) & 1)) >> 16;   // RNE, finite inputs
    return (unsigned short)u;
}

__device__ __forceinline__ float bf2f(unsigned short h) {
    union { unsigned u; float f; } a; a.u = ((unsigned)h) << 16;
    return a.f;
}

__device__ __forceinline__ void async_copy16(const void* gp, void* lp) {
    __builtin_amdgcn_global_load_lds(
        (const __attribute__((address_space(1))) void*)gp,
        (__attribute__((address_space(3))) void*)lp,
        16, 0, 0);
}

// ---- kernel 1: fused x->bf16 (blocks 0..16383) and W->Bt transpose (blocks 16384..18431) ----
__global__ __launch_bounds__(256) void cvt_kernel(
    const float* __restrict__ x, unsigned short* __restrict__ xb,
    const float* __restrict__ W, unsigned short* __restrict__ Bt)
{
    const int blk = blockIdx.x;
    const int t   = threadIdx.x;
    if (blk < 16384) {
        int i = blk * 256 + t;
        float4 v = ((const float4*)x)[i];
        ushort4 o;
        o.x = f2bf(v.x); o.y = f2bf(v.y); o.z = f2bf(v.z); o.w = f2bf(v.w);
        ((ushort4*)xb)[i] = o;
    } else {
        __shared__ float tile[32][33];
        const int b2 = blk - 16384;          // 64 k-tiles x 32 n-tiles
        const int k0 = (b2 & 63) * 32;
        const int n0 = (b2 >> 6) * 32;
        const int tx = t & 31, ty = t >> 5;  // 32 x 8
        #pragma unroll
        for (int i = 0; i < 4; i++) {
            int k = k0 + ty + i * 8;
            int n = n0 + tx;
            tile[ty + i * 8][tx] = (n < CDIM) ? W[(size_t)k * CDIM + n] : 0.0f;
        }
        __syncthreads();
        #pragma unroll
        for (int i = 0; i < 4; i++) {
            int n = n0 + ty + i * 8;
            int k = k0 + tx;
            Bt[(size_t)n * DDIM + k] = f2bf(tile[tx][ty + i * 8]);
        }
    }
}

// ---- GEMM body: R7 XOR-swizzled layout + FULL DMA double-buffer, 1 barrier/iter ----
// Per iter: [barrier: drains DMA(i), issued one full compute phase earlier]
//           [issue DMA(i+1) -> other buffer] [compute tile i].
// WAR safe: DMA(i+2) into buf[i&1] is issued only after the barrier following
// compute(i) (all ds_reads of buf[i&1] complete before each wave's barrier).
// As/Bs are each 2 x 128 x BK bf16 (32 KiB) -> 64 KiB LDS, 2 blocks/CU.
template <bool BF16OUT>
__device__ __forceinline__ void gemm_body(
    const unsigned short* __restrict__ A,
    const unsigned short* __restrict__ Bt,
    void* __restrict__ Cv,
    int mBase, int nBase, int kBase, int kIters,
    unsigned short* As, unsigned short* Bs)
{
    const int t    = threadIdx.x;
    const int wave = t >> 6;
    const int lane = t & 63;
    const int wm   = wave & 1;
    const int wn   = wave >> 1;
    const int quad = lane >> 4;
    const int l16  = lane & 15;

    floatx4 acc[4][4] = {};

    // staging: thread t -> dst slot (rowA = t>>3, chunk c = t&7); fetch the
    // global chunk that belongs there: c' = c ^ (rowA&7). (32r keeps R&7.)
    const int rowA = t >> 3;
    const int csw  = ((t & 7) ^ (rowA & 7)) * 16;   // swizzled source byte col
    const char* Ag = (const char*)A  + ((size_t)(mBase + rowA) * DDIM + kBase) * 2 + csw;
    const char* Bg = (const char*)Bt + ((size_t)(nBase + rowA) * DDIM + kBase) * 2 + csw;
    char* AsDst = (char*)As + t * 16;   // + buf*16384 + r*4096
    char* BsDst = (char*)Bs + t * 16;

    // fragment-read XOR term: chunk cf = ks*4+quad, swizzled by (Rm&7)=(l16&7)
    const int xorb0 = ((0 * 4 + quad) ^ (l16 & 7)) * 8;   // ks=0, ushort units
    const int xorb1 = ((1 * 4 + quad) ^ (l16 & 7)) * 8;   // ks=1

    // prologue: tile 0 -> buffer 0
    #pragma unroll
    for (int r = 0; r < 4; r++) {
        async_copy16(Ag + (size_t)r * 32 * DDIM * 2, AsDst + r * 4096);
        async_copy16(Bg + (size_t)r * 32 * DDIM * 2, BsDst + r * 4096);
    }

    for (int i = 0; i < kIters; i++) {
        __syncthreads();   // drains DMA(i) — issued one full compute phase ago

        if (i + 1 < kIters) {
            const char* a = Ag + (size_t)(i + 1) * BK * 2;
            const char* b = Bg + (size_t)(i + 1) * BK * 2;
            const int bo = ((i + 1) & 1) * 16384;
            #pragma unroll
            for (int r = 0; r < 4; r++) {
                async_copy16(a + (size_t)r * 32 * DDIM * 2, AsDst + bo + r * 4096);
                async_copy16(b + (size_t)r * 32 * DDIM * 2, BsDst + bo + r * 4096);
            }
        }

        const unsigned short* Acur = As + (i & 1) * 8192;   // ushort units
        const unsigned short* Bcur = Bs + (i & 1) * 8192;

        #pragma unroll
        for (int ks = 0; ks < 2; ks++) {
            const int xorb = ks ? xorb1 : xorb0;
            short8 af[4], bfr[4];
            #pragma unroll
            for (int mi = 0; mi < 4; mi++)
                af[mi] = *(const short8*)(Acur + (wm * 64 + mi * 16 + l16) * BK + xorb);
            #pragma unroll
            for (int ni = 0; ni < 4; ni++)
                bfr[ni] = *(const short8*)(Bcur + (wn * 64 + ni * 16 + l16) * BK + xorb);
            #pragma unroll
            for (int mi = 0; mi < 4; mi++)
                #pragma unroll
                for (int ni = 0; ni < 4; ni++)
                    acc[mi][ni] = __builtin_amdgcn_mfma_f32_16x16x32_bf16(
                        af[mi], bfr[ni], acc[mi][ni], 0, 0, 0);
        }
    }

    // C/D layout: col=lane&15, row=quad*4+reg
    #pragma unroll
    for (int mi = 0; mi < 4; mi++) {
        int row0 = mBase + wm * 64 + mi * 16 + quad * 4;
        #pragma unroll
        for (int ni = 0; ni < 4; ni++) {
            int col = nBase + wn * 64 + ni * 16 + l16;
            if (col < CDIM) {
                #pragma unroll
                for (int rg = 0; rg < 4; rg++) {
                    if (BF16OUT)
                        ((unsigned short*)Cv)[(size_t)(row0 + rg) * CDIM + col] =
                            f2bf(acc[mi][ni][rg]);
                    else
                        ((float*)Cv)[(size_t)(row0 + rg) * CDIM + col] = acc[mi][ni][rg];
                }
            }
        }
    }
}

// ---- split-K GEMM: grid 1024, XCD-swizzled; z=0 -> P0, z=1 -> P1 (bf16) ----
__global__ __launch_bounds__(256, 2) void gemm_splitk_kernel(
    const unsigned short* __restrict__ A,
    const unsigned short* __restrict__ Bt,
    unsigned short* __restrict__ P0, unsigned short* __restrict__ P1)
{
    __shared__ unsigned short As[2 * 128 * BK];
    __shared__ unsigned short Bs[2 * 128 * BK];

    const int L   = blockIdx.x;          // 0..1023
    const int xcd = L & 7;
    const int s   = L >> 3;              // 0..127
    const int mz  = xcd * 16 + (s >> 3); // 0..127
    const int n_t = s & 7;
    const int m_t = mz >> 1;             // 0..63
    const int z   = mz & 1;

    unsigned short* P = z ? P1 : P0;
    gemm_body<true>(A, Bt, P, m_t * 128, n_t * 128, z * (DDIM / 2), (DDIM / 2) / BK, As, Bs);
}

// ---- single-K fallback: grid 512, fp32 out ----
__global__ __launch_bounds__(256, 2) void gemm_single_kernel(
    const unsigned short* __restrict__ A,
    const unsigned short* __restrict__ Bt,
    float* __restrict__ C0)
{
    __shared__ unsigned short As[2 * 128 * BK];
    __shared__ unsigned short Bs[2 * 128 * BK];

    const int L   = blockIdx.x;          // 0..511
    const int xcd = L & 7;
    const int s   = L >> 3;              // 0..63
    const int m_t = xcd * 8 + (s >> 3);
    const int n_t = s & 7;

    gemm_body<false>(A, Bt, C0, m_t * 128, n_t * 128, 0, DDIM / BK, As, Bs);
}

// ---- bias + LOO-logsumexp; split: sum two bf16 partials -> fp32 out ----
__global__ __launch_bounds__(256) void lse_kernel(
    float* __restrict__ out,
    const unsigned short* P0, const unsigned short* P1,
    const float* __restrict__ bias, int split)
{
    const int row = blockIdx.x;
    const int t   = threadIdx.x;
    __shared__ float red[8];

    const bool valid = t < (CDIM / 4);   // 250 threads x 4 cols
    const int c0 = t * 4;

    float4 v = make_float4(-INFINITY, -INFINITY, -INFINITY, -INFINITY);
    float4 e = make_float4(0.f, 0.f, 0.f, 0.f);
    if (valid) {
        if (split) {
            ushort4 p0 = *(const ushort4*)(P0 + (size_t)row * CDIM + c0);
            ushort4 p1 = *(const ushort4*)(P1 + (size_t)row * CDIM + c0);
            v.x = bf2f(p0.x) + bf2f(p1.x);
            v.y = bf2f(p0.y) + bf2f(p1.y);
            v.z = bf2f(p0.z) + bf2f(p1.z);
            v.w = bf2f(p0.w) + bf2f(p1.w);
        } else {
            v = *(const float4*)(out + (size_t)row * CDIM + c0);
        }
        float4 bb = *(const float4*)(bias + c0);
        v.x += bb.x; v.y += bb.y; v.z += bb.z; v.w += bb.w;
    }

    float m = fmaxf(fmaxf(v.x, v.y), fmaxf(v.z, v.w));
    #pragma unroll
    for (int off = 32; off > 0; off >>= 1)
        m = fmaxf(m, __shfl_down(m, off, 64));
    const int wave = t >> 6;
    if ((t & 63) == 0) red[wave] = m;
    __syncthreads();
    if (t == 0) red[4] = fmaxf(fmaxf(red[0], red[1]), fmaxf(red[2], red[3]));
    __syncthreads();
    const float M = red[4];

    float s = 0.f;
    if (valid) {
        e.x = expf(v.x - M); e.y = expf(v.y - M);
        e.z = expf(v.z - M); e.w = expf(v.w - M);
        s = e.x + e.y + e.z + e.w;
    }
    #pragma unroll
    for (int off = 32; off > 0; off >>= 1)
        s += __shfl_down(s, off, 64);
    if ((t & 63) == 0) red[wave] = s;
    __syncthreads();
    if (t == 0) red[4] = red[0] + red[1] + red[2] + red[3];
    __syncthreads();
    const float S    = red[4];
    const float lse  = M + logf(S);
    const float invS = 1.0f / S;

    if (valid) {
        float4 o;
        o.x = (v.x - lse) - log1pf(-e.x * invS);
        o.y = (v.y - lse) - log1pf(-e.y * invS);
        o.z = (v.z - lse) - log1pf(-e.z * invS);
        o.w = (v.w - lse) - log1pf(-e.w * invS);
        *(float4*)(out + (size_t)row * CDIM + c0) = o;
    }
}

extern "C" void kernel_launch(void* const* d_in, const int* in_sizes, int n_in,
                              void* d_out, int out_size, void* d_ws, size_t ws_size,
                              hipStream_t stream) {
    const float* x = (const float*)d_in[0];   // [8192, 2048]
    const float* W = (const float*)d_in[1];   // [2048, 1000]
    const float* b = (const float*)d_in[2];   // [1000]
    float* out = (float*)d_out;               // [8192, 1000]

    unsigned short* xb = (unsigned short*)d_ws;
    unsigned short* Bt = (unsigned short*)((char*)d_ws + WS_BT_OFFSET);
    unsigned short* P0 = (unsigned short*)((char*)d_ws + WS_P0_OFFSET);
    unsigned short* P1 = (unsigned short*)((char*)d_ws + WS_P1_OFFSET);
    const bool splitk = ws_size >= WS_NEED;   // constant across calls

    // 1) fused x->bf16 + W->Bt (16384 + 2048 blocks)
    cvt_kernel<<<18432, 256, 0, stream>>>(x, xb, W, Bt);

    // 2) GEMM + 3) LOO-LSE
    if (splitk) {
        gemm_splitk_kernel<<<1024, 256, 0, stream>>>(xb, Bt, P0, P1);
        lse_kernel<<<BDIM, 256, 0, stream>>>(out, P0, P1, b, 1);
    } else {
        gemm_single_kernel<<<512, 256, 0, stream>>>(xb, Bt, out);
        lse_kernel<<<BDIM, 256, 0, stream>>>(out, nullptr, nullptr, b, 0);
    }
}

// Round 10
// 174.145 us; speedup vs baseline: 1.2398x; 1.0267x over previous
//
#include <hip/hip_runtime.h>
#include <hip/hip_bf16.h>
#include <math.h>

#define BDIM 8192
#define DDIM 2048
#define CDIM 1000
#define NPAD 1024
#define BK   64

// ws layout (bytes):
//   xb bf16 [8192*2048] = 33554432 @ 0
//   Bt bf16 [1024*2048] =  4194304 @ 33554432
//   P0 bf16 [8192*1000] = 16384000 @ 37748736   (split-K partial, k-half 0)
//   P1 bf16 [8192*1000] = 16384000 @ 54132736   (split-K partial, k-half 1)
// total = 70516736
#define WS_BT_OFFSET  33554432ULL
#define WS_P0_OFFSET  37748736ULL
#define WS_P1_OFFSET  54132736ULL
#define WS_NEED       70516736ULL

typedef __attribute__((ext_vector_type(8))) short short8;
typedef __attribute__((ext_vector_type(4))) float floatx4;

__device__ __forceinline__ unsigned short f2bf(float f) {
    union { float f; unsigned u; } a; a.f = f;
    unsigned u = a.u;
    u = (u + 0x7fff + ((u >> 16) & 1)) >> 16;   // RNE, finite inputs
    return (unsigned short)u;
}

__device__ __forceinline__ float bf2f(unsigned short h) {
    union { unsigned u; float f; } a; a.u = ((unsigned)h) << 16;
    return a.f;
}

__device__ __forceinline__ void async_copy16(const void* gp, void* lp) {
    __builtin_amdgcn_global_load_lds(
        (const __attribute__((address_space(1))) void*)gp,
        (__attribute__((address_space(3))) void*)lp,
        16, 0, 0);
}

// ---- kernel 1: fused x->bf16 (blocks 0..16383) and W->Bt transpose (blocks 16384..18431) ----
__global__ __launch_bounds__(256) void cvt_kernel(
    const float* __restrict__ x, unsigned short* __restrict__ xb,
    const float* __restrict__ W, unsigned short* __restrict__ Bt)
{
    const int blk = blockIdx.x;
    const int t   = threadIdx.x;
    if (blk < 16384) {
        int i = blk * 256 + t;
        float4 v = ((const float4*)x)[i];
        ushort4 o;
        o.x = f2bf(v.x); o.y = f2bf(v.y); o.z = f2bf(v.z); o.w = f2bf(v.w);
        ((ushort4*)xb)[i] = o;
    } else {
        __shared__ float tile[32][33];
        const int b2 = blk - 16384;          // 64 k-tiles x 32 n-tiles
        const int k0 = (b2 & 63) * 32;
        const int n0 = (b2 >> 6) * 32;
        const int tx = t & 31, ty = t >> 5;  // 32 x 8
        #pragma unroll
        for (int i = 0; i < 4; i++) {
            int k = k0 + ty + i * 8;
            int n = n0 + tx;
            tile[ty + i * 8][tx] = (n < CDIM) ? W[(size_t)k * CDIM + n] : 0.0f;
        }
        __syncthreads();
        #pragma unroll
        for (int i = 0; i < 4; i++) {
            int n = n0 + ty + i * 8;
            int k = k0 + tx;
            Bt[(size_t)n * DDIM + k] = f2bf(tile[tx][ty + i * 8]);
        }
    }
}

// ---- GEMM body: R7 structure (XOR-swizzled LDS, zero bank conflicts) ----
// BF16OUT: store partials as bf16 (split-K path); else fp32 (fallback).
template <bool BF16OUT>
__device__ __forceinline__ void gemm_body(
    const unsigned short* __restrict__ A,
    const unsigned short* __restrict__ Bt,
    void* __restrict__ Cv,
    int mBase, int nBase, int kBase, int kIters,
    unsigned short* As, unsigned short* Bs)
{
    const int t    = threadIdx.x;
    const int wave = t >> 6;
    const int lane = t & 63;
    const int wm   = wave & 1;
    const int wn   = wave >> 1;
    const int quad = lane >> 4;
    const int l16  = lane & 15;

    floatx4 acc[4][4] = {};

    // staging: thread t -> dst slot (rowA = t>>3, chunk c = t&7); fetch the
    // global chunk that belongs there: c' = c ^ (rowA&7). (32r keeps R&7.)
    const int rowA = t >> 3;
    const int csw  = ((t & 7) ^ (rowA & 7)) * 16;   // swizzled source byte col
    const char* Ag = (const char*)A  + ((size_t)(mBase + rowA) * DDIM + kBase) * 2 + csw;
    const char* Bg = (const char*)Bt + ((size_t)(nBase + rowA) * DDIM + kBase) * 2 + csw;
    char* AsDst = (char*)As + t * 16;
    char* BsDst = (char*)Bs + t * 16;

    // fragment-read XOR term: chunk cf = ks*4+quad, swizzled by (Rm&7)=(l16&7)
    const int xorb0 = ((0 * 4 + quad) ^ (l16 & 7)) * 8;   // ks=0, ushort units
    const int xorb1 = ((1 * 4 + quad) ^ (l16 & 7)) * 8;   // ks=1

    for (int kt = 0; kt < kIters * BK; kt += BK) {
        const char* a = Ag + kt * 2;
        const char* b = Bg + kt * 2;
        #pragma unroll
        for (int r = 0; r < 4; r++) {
            async_copy16(a + (size_t)r * 32 * DDIM * 2, AsDst + r * 4096);
            async_copy16(b + (size_t)r * 32 * DDIM * 2, BsDst + r * 4096);
        }
        __syncthreads();

        #pragma unroll
        for (int ks = 0; ks < 2; ks++) {
            const int xorb = ks ? xorb1 : xorb0;
            short8 af[4], bfr[4];
            #pragma unroll
            for (int mi = 0; mi < 4; mi++)
                af[mi] = *(const short8*)(As + (wm * 64 + mi * 16 + l16) * BK + xorb);
            #pragma unroll
            for (int ni = 0; ni < 4; ni++)
                bfr[ni] = *(const short8*)(Bs + (wn * 64 + ni * 16 + l16) * BK + xorb);
            #pragma unroll
            for (int mi = 0; mi < 4; mi++)
                #pragma unroll
                for (int ni = 0; ni < 4; ni++)
                    acc[mi][ni] = __builtin_amdgcn_mfma_f32_16x16x32_bf16(
                        af[mi], bfr[ni], acc[mi][ni], 0, 0, 0);
        }
        __syncthreads();
    }

    // C/D layout: col=lane&15, row=quad*4+reg
    #pragma unroll
    for (int mi = 0; mi < 4; mi++) {
        int row0 = mBase + wm * 64 + mi * 16 + quad * 4;
        #pragma unroll
        for (int ni = 0; ni < 4; ni++) {
            int col = nBase + wn * 64 + ni * 16 + l16;
            if (col < CDIM) {
                #pragma unroll
                for (int rg = 0; rg < 4; rg++) {
                    if (BF16OUT)
                        ((unsigned short*)Cv)[(size_t)(row0 + rg) * CDIM + col] =
                            f2bf(acc[mi][ni][rg]);
                    else
                        ((float*)Cv)[(size_t)(row0 + rg) * CDIM + col] = acc[mi][ni][rg];
                }
            }
        }
    }
}

// ---- split-K GEMM: grid 1024, XCD-swizzled; z=0 -> P0, z=1 -> P1 (bf16) ----
__global__ __launch_bounds__(256, 4) void gemm_splitk_kernel(
    const unsigned short* __restrict__ A,
    const unsigned short* __restrict__ Bt,
    unsigned short* __restrict__ P0, unsigned short* __restrict__ P1)
{
    __shared__ unsigned short As[128 * BK];
    __shared__ unsigned short Bs[128 * BK];

    const int L   = blockIdx.x;          // 0..1023
    const int xcd = L & 7;
    const int s   = L >> 3;              // 0..127
    const int mz  = xcd * 16 + (s >> 3); // 0..127
    const int n_t = s & 7;
    const int m_t = mz >> 1;             // 0..63
    const int z   = mz & 1;

    unsigned short* P = z ? P1 : P0;
    gemm_body<true>(A, Bt, P, m_t * 128, n_t * 128, z * (DDIM / 2), (DDIM / 2) / BK, As, Bs);
}

// ---- single-K fallback: grid 512, fp32 out ----
__global__ __launch_bounds__(256, 2) void gemm_single_kernel(
    const unsigned short* __restrict__ A,
    const unsigned short* __restrict__ Bt,
    float* __restrict__ C0)
{
    __shared__ unsigned short As[128 * BK];
    __shared__ unsigned short Bs[128 * BK];

    const int L   = blockIdx.x;          // 0..511
    const int xcd = L & 7;
    const int s   = L >> 3;              // 0..63
    const int m_t = xcd * 8 + (s >> 3);
    const int n_t = s & 7;

    gemm_body<false>(A, Bt, C0, m_t * 128, n_t * 128, 0, DDIM / BK, As, Bs);
}

// ---- bias + LOO-logsumexp; split: sum two bf16 partials -> fp32 out ----
__global__ __launch_bounds__(256) void lse_kernel(
    float* __restrict__ out,
    const unsigned short* P0, const unsigned short* P1,
    const float* __restrict__ bias, int split)
{
    const int row = blockIdx.x;
    const int t   = threadIdx.x;
    __shared__ float red[8];

    const bool valid = t < (CDIM / 4);   // 250 threads x 4 cols
    const int c0 = t * 4;

    float4 v = make_float4(-INFINITY, -INFINITY, -INFINITY, -INFINITY);
    float4 e = make_float4(0.f, 0.f, 0.f, 0.f);
    if (valid) {
        if (split) {
            // byte offset (row*1000+c0)*2 = 2000*row + 8*t -> 8B aligned
            ushort4 p0 = *(const ushort4*)(P0 + (size_t)row * CDIM + c0);
            ushort4 p1 = *(const ushort4*)(P1 + (size_t)row * CDIM + c0);
            v.x = bf2f(p0.x) + bf2f(p1.x);
            v.y = bf2f(p0.y) + bf2f(p1.y);
            v.z = bf2f(p0.z) + bf2f(p1.z);
            v.w = bf2f(p0.w) + bf2f(p1.w);
        } else {
            v = *(const float4*)(out + (size_t)row * CDIM + c0);
        }
        float4 bb = *(const float4*)(bias + c0);
        v.x += bb.x; v.y += bb.y; v.z += bb.z; v.w += bb.w;
    }

    float m = fmaxf(fmaxf(v.x, v.y), fmaxf(v.z, v.w));
    #pragma unroll
    for (int off = 32; off > 0; off >>= 1)
        m = fmaxf(m, __shfl_down(m, off, 64));
    const int wave = t >> 6;
    if ((t & 63) == 0) red[wave] = m;
    __syncthreads();
    if (t == 0) red[4] = fmaxf(fmaxf(red[0], red[1]), fmaxf(red[2], red[3]));
    __syncthreads();
    const float M = red[4];

    float s = 0.f;
    if (valid) {
        e.x = expf(v.x - M); e.y = expf(v.y - M);
        e.z = expf(v.z - M); e.w = expf(v.w - M);
        s = e.x + e.y + e.z + e.w;
    }
    #pragma unroll
    for (int off = 32; off > 0; off >>= 1)
        s += __shfl_down(s, off, 64);
    if ((t & 63) == 0) red[wave] = s;
    __syncthreads();
    if (t == 0) red[4] = red[0] + red[1] + red[2] + red[3];
    __syncthreads();
    const float S    = red[4];
    const float lse  = M + logf(S);
    const float invS = 1.0f / S;

    if (valid) {
        float4 o;
        o.x = (v.x - lse) - log1pf(-e.x * invS);
        o.y = (v.y - lse) - log1pf(-e.y * invS);
        o.z = (v.z - lse) - log1pf(-e.z * invS);
        o.w = (v.w - lse) - log1pf(-e.w * invS);
        *(float4*)(out + (size_t)row * CDIM + c0) = o;
    }
}

extern "C" void kernel_launch(void* const* d_in, const int* in_sizes, int n_in,
                              void* d_out, int out_size, void* d_ws, size_t ws_size,
                              hipStream_t stream) {
    const float* x = (const float*)d_in[0];   // [8192, 2048]
    const float* W = (const float*)d_in[1];   // [2048, 1000]
    const float* b = (const float*)d_in[2];   // [1000]
    float* out = (float*)d_out;               // [8192, 1000]

    unsigned short* xb = (unsigned short*)d_ws;
    unsigned short* Bt = (unsigned short*)((char*)d_ws + WS_BT_OFFSET);
    unsigned short* P0 = (unsigned short*)((char*)d_ws + WS_P0_OFFSET);
    unsigned short* P1 = (unsigned short*)((char*)d_ws + WS_P1_OFFSET);
    const bool splitk = ws_size >= WS_NEED;   // constant across calls

    // 1) fused x->bf16 + W->Bt (16384 + 2048 blocks)
    cvt_kernel<<<18432, 256, 0, stream>>>(x, xb, W, Bt);

    // 2) GEMM + 3) LOO-LSE
    if (splitk) {
        gemm_splitk_kernel<<<1024, 256, 0, stream>>>(xb, Bt, P0, P1);
        lse_kernel<<<BDIM, 256, 0, stream>>>(out, P0, P1, b, 1);
    } else {
        gemm_single_kernel<<<512, 256, 0, stream>>>(xb, Bt, out);
        lse_kernel<<<BDIM, 256, 0, stream>>>(out, nullptr, nullptr, b, 0);
    }
}